// Round 10
// baseline (87.908 us; speedup 1.0000x reference)
//
#include <hip/hip_runtime.h>
#include <math.h>

#define THREADS 256
#define NTASK (56 * 3 * 28)
#define CROP_BLOCKS 1024

typedef float f32x4 __attribute__((ext_vector_type(4)));
typedef const __attribute__((address_space(1))) float ga_float;
typedef __attribute__((address_space(3))) float lds_float;

// ---------------- Launch 1: chansum (8*K blocks) + logits1 (128 blocks) ---
__global__ __launch_bounds__(THREADS) void fused1_kernel(const float* __restrict__ fm,
                                                         float4* __restrict__ part,
                                                         int cpc, int K,
                                                         const float* __restrict__ emb,
                                                         const float* __restrict__ W,
                                                         float* __restrict__ lpart,
                                                         int* __restrict__ done) {
    int blk = blockIdx.x;
    int t = threadIdx.x;
    if (blk == 0 && t == 0)
        __hip_atomic_store(done, 0, __ATOMIC_RELAXED, __HIP_MEMORY_SCOPE_AGENT);
    if (blk < 8 * K) {
        int b = blk / K, k = blk - b * K;
        if (t >= 196) return;
        const float4* f = (const float4*)(fm + ((size_t)b * 384 + (size_t)k * cpc) * 784);
        float4 acc = {0.0f, 0.0f, 0.0f, 0.0f};
        for (int c = 0; c < cpc; ++c) {
            float4 v = f[(size_t)c * 196 + t];
            acc.x += v.x; acc.y += v.y; acc.z += v.z; acc.w += v.w;
        }
        part[((size_t)b * K + k) * 196 + t] = acc;
    } else {
        int idx = blk - 8 * K;
        int b = idx >> 4, kc = idx & 15;
        if (t >= 200) return;
        const float* e  = emb + (size_t)b * 2048 + kc * 128;
        const float* wp = W + (size_t)kc * 128 * 200 + t;
        float acc = 0.0f;
        #pragma unroll 4
        for (int k = 0; k < 128; ++k)
            acc += e[k] * wp[(size_t)k * 200];
        lpart[((size_t)b * 16 + kc) * 200 + t] = acc;
    }
}

// ---------------- crop task geometry -------------------------------------
struct Geo {
    int w, rlo, S;
    float scale, wm1;
    const float* base;
    float* outp;
};

__device__ __forceinline__ Geo geo(int task, const float* __restrict__ x,
                                   const int* __restrict__ coords,
                                   const int* __restrict__ ws_idx,
                                   float* __restrict__ imgs) {
    Geo G;
    int p = task / 84, rem = task - p * 84;
    int ch = rem / 28, stripe = rem - ch * 28;
    int b = p / 7, col = p - b * 7;
    int g = (col < 2) ? 0 : ((col < 5) ? 1 : 2);
    G.w = (g == 0) ? 64 : ((g == 1) ? 96 : 128);
    G.scale = (float)G.w * (1.0f / 448.0f);
    G.wm1 = (float)(G.w - 1);
    G.S = stripe * 16;
    float syb = fminf(fmaxf(((float)G.S + 0.5f) * G.scale - 0.5f, 0.0f), G.wm1);
    G.rlo = (int)syb;
    int gi = __hip_atomic_load(&ws_idx[p], __ATOMIC_RELAXED, __HIP_MEMORY_SCOPE_AGENT);
    int c0 = coords[gi * 4 + 0];
    int c1 = coords[gi * 4 + 1];
    G.base = x + (((size_t)b * 3 + ch) * 448) * 448 + c1 + (size_t)c0 * 448;
    G.outp = imgs + (((size_t)p * 3 + ch) * 448) * 448;
    return G;
}

// ---------------- Launch 2: NMS (0..23) + logits2 (24..31) + crop (32..) --
__global__ __launch_bounds__(448) void mega_kernel(const float4* __restrict__ part,
                                                   int K,
                                                   float* __restrict__ all_scores,
                                                   float* __restrict__ out_idx_f,
                                                   float* __restrict__ out_sc,
                                                   int* __restrict__ ws_idx,
                                                   const float* __restrict__ lpart,
                                                   const float* __restrict__ bias,
                                                   float* __restrict__ logits,
                                                   const float* __restrict__ x,
                                                   const int* __restrict__ coords,
                                                   float* __restrict__ imgs,
                                                   int* __restrict__ done) {
    __shared__ float4 s4[196];
    __shared__ float  pref[28][29];
    __shared__ float  scl[625];
    __shared__ float  rv[7];
    __shared__ int    ri[7];
    __shared__ float  lds[2][7 * 132];
    int t = threadIdx.x;
    int bid = blockIdx.x;

    if (bid >= 24 && bid < 32) {     // ---- logits2 ----
        int b = bid - 24;
        if (t >= 200) return;
        float acc = bias[t];
        #pragma unroll
        for (int kc = 0; kc < 16; ++kc)
            acc += lpart[((size_t)b * 16 + kc) * 200 + t];
        logits[b * 200 + t] = acc;
        return;
    }

    if (bid < 24) {                  // ---- score + NMS per (batch, group) ----
        int b = bid / 3, g = bid - b * 3;

        if (t < 196) {
            float4 acc = {0.0f, 0.0f, 0.0f, 0.0f};
            #pragma unroll 8
            for (int k = 0; k < K; ++k) {
                float4 v = part[((size_t)b * K + k) * 196 + t];
                acc.x += v.x; acc.y += v.y; acc.z += v.z; acc.w += v.w;
            }
            s4[t] = acc;
        }
        __syncthreads();
        if (t < 28) {
            float4 row[7];
            #pragma unroll
            for (int i = 0; i < 7; ++i) row[i] = s4[t * 7 + i];
            float run = 0.0f;
            pref[t][0] = 0.0f;
            #pragma unroll
            for (int j = 0; j < 28; ++j) {
                run += ((float*)row)[j];
                pref[t][j + 1] = run;
            }
        }
        __syncthreads();

        const int gnA[3]   = {625, 529, 441};
        const int sideA[3] = {25, 23, 21};
        const int rA[3]    = {4, 6, 8};
        const int nselA[3] = {2, 3, 2};
        const int colA[3]  = {0, 2, 5};
        const int goffA[3] = {0, 625, 1154};

        int n = gnA[g], side = sideA[g], r = rA[g];
        int nsel = nselA[g], goff = goffA[g], colbase = colA[g];
        float inv = 1.0f / (float)(r * r);

        for (int loc = t; loc < n; loc += 448) {
            int i = loc / side, j = loc % side;
            float acc = 0.0f;
            for (int a = 0; a < r; ++a)
                acc += pref[i + a][j + r] - pref[i + a][j];
            float sv = acc * inv;
            scl[loc] = sv;
            all_scores[b * 1595 + goff + loc] = sv;
        }
        __syncthreads();

        float ext = (float)(r * 16 + 1);
        float A   = ext * ext;
        float rs  = (float)(r * 16);

        for (int k = 0; k < nsel; ++k) {
            float bv = -INFINITY; int bi = 0x7fffffff;
            for (int i = t; i < n; i += 448) {
                float v = scl[i];
                if (v > bv || (v == bv && i < bi)) { bv = v; bi = i; }
            }
            #pragma unroll
            for (int m = 1; m < 64; m <<= 1) {
                float ov = __shfl_xor(bv, m, 64);
                int   oi = __shfl_xor(bi, m, 64);
                if (ov > bv || (ov == bv && oi < bi)) { bv = ov; bi = oi; }
            }
            int wv = t >> 6;
            if ((t & 63) == 0) { rv[wv] = bv; ri[wv] = bi; }
            __syncthreads();
            if (t == 0) {
                for (int q = 1; q < 7; ++q) {
                    float ov = rv[q]; int oi = ri[q];
                    if (ov > bv || (ov == bv && oi < bi)) { bv = ov; bi = oi; }
                }
                ri[0] = bi;
                int outp = b * 7 + colbase + k;
                out_idx_f[outp] = (float)(goff + bi);
                out_sc[outp]    = bv;
                __hip_atomic_store(&ws_idx[outp], goff + bi,
                                   __ATOMIC_RELAXED, __HIP_MEMORY_SCOPE_AGENT);
            }
            __syncthreads();
            int sel = ri[0];
            int si = sel / side, sj = sel % side;
            float sx0 = si * 16.0f, sy0 = sj * 16.0f;
            float sx1 = sx0 + rs,   sy1 = sy0 + rs;
            for (int i = t; i < n; i += 448) {
                int ii = i / side, jj = i % side;
                float x0 = ii * 16.0f, y0 = jj * 16.0f;
                float x1 = x0 + rs,    y1 = y0 + rs;
                float xx0 = fmaxf(x0, sx0), yy0 = fmaxf(y0, sy0);
                float xx1 = fminf(x1, sx1), yy1 = fminf(y1, sy1);
                float w = xx1 - xx0 + 1.0f, h = yy1 - yy0 + 1.0f;
                float inter = (w < 0.0f || h < 0.0f) ? 0.0f : w * h;
                float iou = inter / (A + A - inter);
                if (iou > 0.25f) scl[i] = -INFINITY;
            }
            __syncthreads();
        }
        if (t == 0)
            __hip_atomic_fetch_add(done, 1, __ATOMIC_RELEASE, __HIP_MEMORY_SCOPE_AGENT);
        return;
    }

    // ---- crop: persistent, async global_load_lds double-buffer ----
    if (t == 0) {
        while (__hip_atomic_load(done, __ATOMIC_ACQUIRE, __HIP_MEMORY_SCOPE_AGENT) < 24)
            __builtin_amdgcn_s_sleep(2);
    }
    __syncthreads();

    int cb = bid - 32;
    int r4   = t / 33;               // staged row (t < 231)
    int c4x4 = (t - r4 * 33) * 4;    // staged col base
    int row_sub = t / 56;            // 0..7
    int seg     = t - row_sub * 56;  // 0..55
    int ox0 = seg * 8;

    int task = cb;
    Geo Gc = geo(task, x, coords, ws_idx, imgs);
    if (t < 231) {
        const float* ga = Gc.base + (size_t)min(Gc.rlo + r4, Gc.w - 1) * 448
                        + min(c4x4, Gc.w - 4);
        __builtin_amdgcn_global_load_lds((ga_float*)ga, (lds_float*)&lds[0][t * 4], 16, 0, 0);
    }
    int buf = 0;

    while (true) {
        int nxt = task + CROP_BLOCKS;
        bool has = nxt < NTASK;
        __syncthreads();             // drains DMA for lds[buf] (issued a full task ago)

        Geo Gn;
        if (has) {
            Gn = geo(nxt, x, coords, ws_idx, imgs);
            if (t < 231) {
                const float* ga = Gn.base + (size_t)min(Gn.rlo + r4, Gn.w - 1) * 448
                                + min(c4x4, Gn.w - 4);
                __builtin_amdgcn_global_load_lds((ga_float*)ga,
                                                 (lds_float*)&lds[buf ^ 1][t * 4], 16, 0, 0);
            }
        }

        // ---- compute current task: 2 output rows x 8 cols per thread ----
        {
            float sxb = ((float)ox0 + 0.5f) * Gc.scale - 0.5f;
            float sxc = fminf(fmaxf(sxb, 0.0f), Gc.wm1);
            int   i0  = (int)sxc;
            int   dk[8];
            float txk[8];
            #pragma unroll
            for (int k = 0; k < 8; ++k) {
                float sx = fminf(fmaxf(sxb + (float)k * Gc.scale, 0.0f), Gc.wm1);
                int xi = (int)sx;
                dk[k]  = xi - i0;          // 0, 1, or 2
                txk[k] = sx - (float)xi;
            }
            const float* lbase = &lds[buf][0];
            #pragma unroll
            for (int half = 0; half < 2; ++half) {
                int oy = Gc.S + half * 8 + row_sub;
                float sy = fminf(fmaxf(((float)oy + 0.5f) * Gc.scale - 0.5f, 0.0f), Gc.wm1);
                int   y0 = (int)sy;
                int   y1 = min(y0 + 1, Gc.w - 1);
                float ty = sy - (float)y0;
                const float* l0 = lbase + (y0 - Gc.rlo) * 132 + i0;
                const float* l1 = lbase + (y1 - Gc.rlo) * 132 + i0;
                float a0 = l0[0], a1 = l0[1], a2 = l0[2], a3 = l0[3];
                float b0 = l1[0], b1 = l1[1], b2 = l1[2], b3 = l1[3];

                f32x4 res0, res1;
                #pragma unroll
                for (int k = 0; k < 8; ++k) {
                    int   d   = dk[k];
                    float v00 = (d == 0) ? a0 : ((d == 1) ? a1 : a2);
                    float v01 = (d == 0) ? a1 : ((d == 1) ? a2 : a3);
                    float v10 = (d == 0) ? b0 : ((d == 1) ? b1 : b2);
                    float v11 = (d == 0) ? b1 : ((d == 1) ? b2 : b3);
                    float tx  = txk[k];
                    float top = v00 + tx * (v01 - v00);
                    float bot = v10 + tx * (v11 - v10);
                    float rr  = top + ty * (bot - top);
                    if (k < 4) res0[k] = rr; else res1[k - 4] = rr;
                }
                float* orow = Gc.outp + (size_t)oy * 448 + ox0;
                *(f32x4*)orow       = res0;
                *(f32x4*)(orow + 4) = res1;
            }
        }

        if (!has) break;
        Gc = Gn; buf ^= 1; task = nxt;
    }
}

extern "C" void kernel_launch(void* const* d_in, const int* in_sizes, int n_in,
                              void* d_out, int out_size, void* d_ws, size_t ws_size,
                              hipStream_t stream) {
    const float* x      = (const float*)d_in[0];   // (8,3,448,448)
    const float* fm     = (const float*)d_in[1];   // (8,384,28,28)
    const float* emb    = (const float*)d_in[2];   // (8,2048)
    const float* Wc     = (const float*)d_in[3];   // (2048,200)
    const float* bc     = (const float*)d_in[4];   // (200,)
    const int*   coords = (const int*)d_in[5];     // (1595,4)

    float* out        = (float*)d_out;
    float* out_idx    = out;                  // 56  (indices, stored as float)
    float* out_sc     = out + 56;             // 56
    float* all_scores = out + 112;            // 12760
    float* imgs       = out + 12872;          // 33718272
    float* logits     = out + 33731144;       // 1600

    int K = 32;
    while (K > 1 && ws_size < 1024 + (size_t)8 * K * 784 * 4 + 25600 * 4) K >>= 1;
    int cpc = 384 / K;

    int*    ws_idx = (int*)d_ws;                                   // 56 ints
    int*    done   = (int*)((char*)d_ws + 512);                    // sync counter
    float4* part   = (float4*)((char*)d_ws + 1024);                // 8*K*196 float4
    float*  lpart  = (float*)((char*)d_ws + 1024 + (size_t)8 * K * 784 * 4);

    fused1_kernel<<<8 * K + 128, THREADS, 0, stream>>>(fm, part, cpc, K, emb, Wc, lpart, done);
    mega_kernel<<<32 + CROP_BLOCKS, 448, 0, stream>>>(part, K, all_scores, out_idx, out_sc,
                                                      ws_idx, lpart, bc, logits,
                                                      x, coords, imgs, done);
}

// Round 11
// 65.068 us; speedup vs baseline: 1.3510x; 1.3510x over previous
//
#include <hip/hip_runtime.h>
#include <math.h>

#define THREADS 256
#define CROP_GRID 1024
#define NTASK (56 * 3 * 28)

typedef float f32x4 __attribute__((ext_vector_type(4)));
typedef float f32x4u __attribute__((ext_vector_type(4), aligned(4)));

// ---------------- Launch 1: chansum (8*K blocks) + logits1 (128 blocks) ---
__global__ __launch_bounds__(THREADS) void fused1_kernel(const float* __restrict__ fm,
                                                         float4* __restrict__ part,
                                                         int cpc, int K,
                                                         const float* __restrict__ emb,
                                                         const float* __restrict__ W,
                                                         float* __restrict__ lpart) {
    int blk = blockIdx.x;
    int t = threadIdx.x;
    if (blk < 8 * K) {
        int b = blk / K, k = blk - b * K;
        if (t >= 196) return;
        const float4* f = (const float4*)(fm + ((size_t)b * 384 + (size_t)k * cpc) * 784);
        float4 acc = {0.0f, 0.0f, 0.0f, 0.0f};
        for (int c = 0; c < cpc; ++c) {
            float4 v = f[(size_t)c * 196 + t];
            acc.x += v.x; acc.y += v.y; acc.z += v.z; acc.w += v.w;
        }
        part[((size_t)b * K + k) * 196 + t] = acc;
    } else {
        int idx = blk - 8 * K;
        int b = idx >> 4, kc = idx & 15;
        if (t >= 200) return;
        const float* e  = emb + (size_t)b * 2048 + kc * 128;
        const float* wp = W + (size_t)kc * 128 * 200 + t;
        float acc = 0.0f;
        #pragma unroll 4
        for (int k = 0; k < 128; ++k)
            acc += e[k] * wp[(size_t)k * 200];
        lpart[((size_t)b * 16 + kc) * 200 + t] = acc;
    }
}

// ---------------- Launch 2: score+NMS (24 blocks) + logits2 (8 blocks) ----
__global__ __launch_bounds__(THREADS) void fused2_kernel(const float4* __restrict__ part,
                                                         int K,
                                                         float* __restrict__ all_scores,
                                                         float* __restrict__ out_idx_f,
                                                         float* __restrict__ out_sc,
                                                         int* __restrict__ ws_idx,
                                                         const float* __restrict__ lpart,
                                                         const float* __restrict__ bias,
                                                         float* __restrict__ logits) {
    __shared__ float4 s4[196];
    __shared__ float  pref[28][29];
    __shared__ float  scl[625];
    __shared__ float  rv[4];
    __shared__ int    ri[4];
    int t = threadIdx.x;

    if (blockIdx.x >= 24) {          // logits2: reduce partials + bias, 1 block/batch
        int b = blockIdx.x - 24;
        if (t >= 200) return;
        float acc = bias[t];
        #pragma unroll
        for (int kc = 0; kc < 16; ++kc)
            acc += lpart[((size_t)b * 16 + kc) * 200 + t];
        logits[b * 200 + t] = acc;
        return;
    }

    int b = blockIdx.x / 3, g = blockIdx.x - b * 3;

    if (t < 196) {
        float4 acc = {0.0f, 0.0f, 0.0f, 0.0f};
        #pragma unroll 8
        for (int k = 0; k < K; ++k) {
            float4 v = part[((size_t)b * K + k) * 196 + t];
            acc.x += v.x; acc.y += v.y; acc.z += v.z; acc.w += v.w;
        }
        s4[t] = acc;
    }
    __syncthreads();
    if (t < 28) {
        float4 row[7];
        #pragma unroll
        for (int i = 0; i < 7; ++i) row[i] = s4[t * 7 + i];
        float run = 0.0f;
        pref[t][0] = 0.0f;
        #pragma unroll
        for (int j = 0; j < 28; ++j) {
            run += ((float*)row)[j];
            pref[t][j + 1] = run;
        }
    }
    __syncthreads();

    const int gnA[3]   = {625, 529, 441};
    const int sideA[3] = {25, 23, 21};
    const int rA[3]    = {4, 6, 8};
    const int nselA[3] = {2, 3, 2};
    const int colA[3]  = {0, 2, 5};
    const int goffA[3] = {0, 625, 1154};

    int n = gnA[g], side = sideA[g], r = rA[g];
    int nsel = nselA[g], goff = goffA[g], colbase = colA[g];
    float inv = 1.0f / (float)(r * r);

    for (int loc = t; loc < n; loc += THREADS) {
        int i = loc / side, j = loc % side;
        float acc = 0.0f;
        for (int a = 0; a < r; ++a)
            acc += pref[i + a][j + r] - pref[i + a][j];
        float sv = acc * inv;
        scl[loc] = sv;
        all_scores[b * 1595 + goff + loc] = sv;
    }
    __syncthreads();

    float ext = (float)(r * 16 + 1);
    float A   = ext * ext;
    float rs  = (float)(r * 16);

    for (int k = 0; k < nsel; ++k) {
        float bv = -INFINITY; int bi = 0x7fffffff;
        for (int i = t; i < n; i += THREADS) {
            float v = scl[i];
            if (v > bv || (v == bv && i < bi)) { bv = v; bi = i; }
        }
        #pragma unroll
        for (int m = 1; m < 64; m <<= 1) {
            float ov = __shfl_xor(bv, m, 64);
            int   oi = __shfl_xor(bi, m, 64);
            if (ov > bv || (ov == bv && oi < bi)) { bv = ov; bi = oi; }
        }
        int wv = t >> 6;
        if ((t & 63) == 0) { rv[wv] = bv; ri[wv] = bi; }
        __syncthreads();
        if (t == 0) {
            for (int q = 1; q < 4; ++q) {
                float ov = rv[q]; int oi = ri[q];
                if (ov > bv || (ov == bv && oi < bi)) { bv = ov; bi = oi; }
            }
            ri[0] = bi;
            int outp = b * 7 + colbase + k;
            out_idx_f[outp] = (float)(goff + bi);
            out_sc[outp]    = bv;
            ws_idx[outp]    = goff + bi;
        }
        __syncthreads();
        int sel = ri[0];
        int si = sel / side, sj = sel % side;
        float sx0 = si * 16.0f, sy0 = sj * 16.0f;
        float sx1 = sx0 + rs,   sy1 = sy0 + rs;
        for (int i = t; i < n; i += THREADS) {
            int ii = i / side, jj = i % side;
            float x0 = ii * 16.0f, y0 = jj * 16.0f;
            float x1 = x0 + rs,    y1 = y0 + rs;
            float xx0 = fmaxf(x0, sx0), yy0 = fmaxf(y0, sy0);
            float xx1 = fminf(x1, sx1), yy1 = fminf(y1, sy1);
            float w = xx1 - xx0 + 1.0f, h = yy1 - yy0 + 1.0f;
            float inter = (w < 0.0f || h < 0.0f) ? 0.0f : w * h;
            float iou = inter / (A + A - inter);
            if (iou > 0.25f) scl[i] = -INFINITY;
        }
        __syncthreads();
    }
}

// ---------------- Launch 3: direct-gather crop (no LDS, no barriers) ------
// x (4.8 MB) is L2/L3-resident (measured FETCH ~8 MB), so LDS staging is
// pure overhead. Task = (p, ch, 16-row stripe); persistent 1024 blocks.
// Each thread: 8 cols on two output rows. The 4 x-taps are 4 CONSECUTIVE
// floats -> one align-4 dwordx4 per source row (4 loads, 4 stores / task).
__global__ __launch_bounds__(448) void crop_kernel(const float* __restrict__ x,
                                                   const int* __restrict__ coords,
                                                   const int* __restrict__ ws_idx,
                                                   float* __restrict__ out) {
    int t = threadIdx.x;
    int row_sub = t / 56;              // 0..7
    int seg     = t - row_sub * 56;    // 0..55
    int ox0 = seg * 8;

    for (int task = blockIdx.x; task < NTASK; task += CROP_GRID) {
        int p = task / 84, rem = task - p * 84;
        int ch = rem / 28, stripe = rem - ch * 28;
        int b = p / 7, col = p - b * 7;
        int g = (col < 2) ? 0 : ((col < 5) ? 1 : 2);
        int w = (g == 0) ? 64 : ((g == 1) ? 96 : 128);
        float scale = (float)w * (1.0f / 448.0f);
        float wm1   = (float)(w - 1);
        int S = stripe * 16;
        int gi = ws_idx[p];
        int c0 = coords[gi * 4 + 0];
        int c1 = coords[gi * 4 + 1];
        const float* base = x + (((size_t)b * 3 + ch) * 448) * 448 + c1 + (size_t)c0 * 448;
        float* outb = out + (((size_t)p * 3 + ch) * 448) * 448;

        // ---- x geometry (shared by both output rows) ----
        float sxb = ((float)ox0 + 0.5f) * scale - 0.5f;
        float sxc = fminf(fmaxf(sxb, 0.0f), wm1);
        int   ib  = min((int)sxc, w - 4);       // window [ib, ib+3], in-bounds
        int   i0k[8], i1k[8];
        float txk[8];
        #pragma unroll
        for (int k = 0; k < 8; ++k) {
            float sx = fminf(fmaxf(sxb + (float)k * scale, 0.0f), wm1);
            int xi = (int)sx;
            txk[k] = sx - (float)xi;
            i0k[k] = xi - ib;                   // 0..3
            i1k[k] = min(xi + 1, w - 1) - ib;   // 0..3 (edge-clamped tap)
        }

        // ---- y geometry + all 4 row loads up front (ILP) ----
        int   y0h[2], y1h[2];
        float tyh[2];
        #pragma unroll
        for (int h = 0; h < 2; ++h) {
            int oy = S + h * 8 + row_sub;
            float sy = fminf(fmaxf(((float)oy + 0.5f) * scale - 0.5f, 0.0f), wm1);
            int y0 = (int)sy;
            y0h[h] = y0;
            y1h[h] = min(y0 + 1, w - 1);
            tyh[h] = sy - (float)y0;
        }
        f32x4 r00 = *(const f32x4u*)(base + (size_t)y0h[0] * 448 + ib);
        f32x4 r01 = *(const f32x4u*)(base + (size_t)y1h[0] * 448 + ib);
        f32x4 r10 = *(const f32x4u*)(base + (size_t)y0h[1] * 448 + ib);
        f32x4 r11 = *(const f32x4u*)(base + (size_t)y1h[1] * 448 + ib);

        #pragma unroll
        for (int h = 0; h < 2; ++h) {
            f32x4 ra = h ? r10 : r00;
            f32x4 rb = h ? r11 : r01;
            float ty = tyh[h];
            int oy = S + h * 8 + row_sub;
            f32x4 res0, res1;
            #pragma unroll
            for (int k = 0; k < 8; ++k) {
                int ia = i0k[k], ic = i1k[k];
                float v00 = (ia == 0) ? ra[0] : ((ia == 1) ? ra[1] : ((ia == 2) ? ra[2] : ra[3]));
                float v01 = (ic == 0) ? ra[0] : ((ic == 1) ? ra[1] : ((ic == 2) ? ra[2] : ra[3]));
                float v10 = (ia == 0) ? rb[0] : ((ia == 1) ? rb[1] : ((ia == 2) ? rb[2] : rb[3]));
                float v11 = (ic == 0) ? rb[0] : ((ic == 1) ? rb[1] : ((ic == 2) ? rb[2] : rb[3]));
                float tx  = txk[k];
                float top = v00 + tx * (v01 - v00);
                float bot = v10 + tx * (v11 - v10);
                float rr  = top + ty * (bot - top);
                if (k < 4) res0[k] = rr; else res1[k - 4] = rr;
            }
            float* orow = outb + (size_t)oy * 448 + ox0;
            *(f32x4*)orow       = res0;
            *(f32x4*)(orow + 4) = res1;
        }
    }
}

extern "C" void kernel_launch(void* const* d_in, const int* in_sizes, int n_in,
                              void* d_out, int out_size, void* d_ws, size_t ws_size,
                              hipStream_t stream) {
    const float* x      = (const float*)d_in[0];   // (8,3,448,448)
    const float* fm     = (const float*)d_in[1];   // (8,384,28,28)
    const float* emb    = (const float*)d_in[2];   // (8,2048)
    const float* Wc     = (const float*)d_in[3];   // (2048,200)
    const float* bc     = (const float*)d_in[4];   // (200,)
    const int*   coords = (const int*)d_in[5];     // (1595,4)

    float* out        = (float*)d_out;
    float* out_idx    = out;                  // 56  (indices, stored as float)
    float* out_sc     = out + 56;             // 56
    float* all_scores = out + 112;            // 12760
    float* imgs       = out + 12872;          // 33718272
    float* logits     = out + 33731144;       // 1600

    int K = 32;
    while (K > 1 && ws_size < 1024 + (size_t)8 * K * 784 * 4 + 25600 * 4) K >>= 1;
    int cpc = 384 / K;

    int*    ws_idx = (int*)d_ws;                                   // 56 ints
    float4* part   = (float4*)((char*)d_ws + 1024);                // 8*K*196 float4
    float*  lpart  = (float*)((char*)d_ws + 1024 + (size_t)8 * K * 784 * 4);

    fused1_kernel<<<8 * K + 128, THREADS, 0, stream>>>(fm, part, cpc, K, emb, Wc, lpart);
    fused2_kernel<<<32, THREADS, 0, stream>>>(part, K, all_scores, out_idx, out_sc, ws_idx,
                                              lpart, bc, logits);
    crop_kernel<<<CROP_GRID, 448, 0, stream>>>(x, coords, ws_idx, imgs);
}

// Round 12
// 54.248 us; speedup vs baseline: 1.6205x; 1.1995x over previous
//
#include <hip/hip_runtime.h>
#include <math.h>

#define THREADS 256
#define CROP_GRID 944
#define NTASK (56 * 3 * 28)

typedef float f32x4 __attribute__((ext_vector_type(4)));

// ---------------- Launch 1: chansum (8*K blocks) + logits1 (128 blocks) ---
__global__ __launch_bounds__(THREADS) void fused1_kernel(const float* __restrict__ fm,
                                                         float4* __restrict__ part,
                                                         int cpc, int K,
                                                         const float* __restrict__ emb,
                                                         const float* __restrict__ W,
                                                         float* __restrict__ lpart) {
    int blk = blockIdx.x;
    int t = threadIdx.x;
    if (blk < 8 * K) {
        int b = blk / K, k = blk - b * K;
        if (t >= 196) return;
        const float4* f = (const float4*)(fm + ((size_t)b * 384 + (size_t)k * cpc) * 784);
        float4 acc = {0.0f, 0.0f, 0.0f, 0.0f};
        for (int c = 0; c < cpc; ++c) {
            float4 v = f[(size_t)c * 196 + t];
            acc.x += v.x; acc.y += v.y; acc.z += v.z; acc.w += v.w;
        }
        part[((size_t)b * K + k) * 196 + t] = acc;
    } else {
        int idx = blk - 8 * K;
        int b = idx >> 4, kc = idx & 15;
        if (t >= 200) return;
        const float* e  = emb + (size_t)b * 2048 + kc * 128;
        const float* wp = W + (size_t)kc * 128 * 200 + t;
        float acc = 0.0f;
        #pragma unroll 4
        for (int k = 0; k < 128; ++k)
            acc += e[k] * wp[(size_t)k * 200];
        lpart[((size_t)b * 16 + kc) * 200 + t] = acc;
    }
}

// ---------------- Launch 2: score+NMS (24 blocks) + logits2 (8 blocks) ----
__global__ __launch_bounds__(THREADS) void fused2_kernel(const float4* __restrict__ part,
                                                         int K,
                                                         float* __restrict__ all_scores,
                                                         float* __restrict__ out_idx_f,
                                                         float* __restrict__ out_sc,
                                                         int* __restrict__ ws_idx,
                                                         int* __restrict__ soff,
                                                         const int* __restrict__ coords,
                                                         const float* __restrict__ lpart,
                                                         const float* __restrict__ bias,
                                                         float* __restrict__ logits) {
    __shared__ float4 s4[196];
    __shared__ float  pref[28][29];
    __shared__ float  scl[625];
    __shared__ float  rv[4];
    __shared__ int    ri[4];
    int t = threadIdx.x;

    if (blockIdx.x >= 24) {          // logits2: reduce partials + bias, 1 block/batch
        int b = blockIdx.x - 24;
        if (t >= 200) return;
        float acc = bias[t];
        #pragma unroll
        for (int kc = 0; kc < 16; ++kc)
            acc += lpart[((size_t)b * 16 + kc) * 200 + t];
        logits[b * 200 + t] = acc;
        return;
    }

    int b = blockIdx.x / 3, g = blockIdx.x - b * 3;

    if (t < 196) {
        float4 acc = {0.0f, 0.0f, 0.0f, 0.0f};
        #pragma unroll 8
        for (int k = 0; k < K; ++k) {
            float4 v = part[((size_t)b * K + k) * 196 + t];
            acc.x += v.x; acc.y += v.y; acc.z += v.z; acc.w += v.w;
        }
        s4[t] = acc;
    }
    __syncthreads();
    if (t < 28) {
        float4 row[7];
        #pragma unroll
        for (int i = 0; i < 7; ++i) row[i] = s4[t * 7 + i];
        float run = 0.0f;
        pref[t][0] = 0.0f;
        #pragma unroll
        for (int j = 0; j < 28; ++j) {
            run += ((float*)row)[j];
            pref[t][j + 1] = run;
        }
    }
    __syncthreads();

    const int gnA[3]   = {625, 529, 441};
    const int sideA[3] = {25, 23, 21};
    const int rA[3]    = {4, 6, 8};
    const int nselA[3] = {2, 3, 2};
    const int colA[3]  = {0, 2, 5};
    const int goffA[3] = {0, 625, 1154};

    int n = gnA[g], side = sideA[g], r = rA[g];
    int nsel = nselA[g], goff = goffA[g], colbase = colA[g];
    float inv = 1.0f / (float)(r * r);

    for (int loc = t; loc < n; loc += THREADS) {
        int i = loc / side, j = loc % side;
        float acc = 0.0f;
        for (int a = 0; a < r; ++a)
            acc += pref[i + a][j + r] - pref[i + a][j];
        float sv = acc * inv;
        scl[loc] = sv;
        all_scores[b * 1595 + goff + loc] = sv;
    }
    __syncthreads();

    float ext = (float)(r * 16 + 1);
    float A   = ext * ext;
    float rs  = (float)(r * 16);

    for (int k = 0; k < nsel; ++k) {
        float bv = -INFINITY; int bi = 0x7fffffff;
        for (int i = t; i < n; i += THREADS) {
            float v = scl[i];
            if (v > bv || (v == bv && i < bi)) { bv = v; bi = i; }
        }
        #pragma unroll
        for (int m = 1; m < 64; m <<= 1) {
            float ov = __shfl_xor(bv, m, 64);
            int   oi = __shfl_xor(bi, m, 64);
            if (ov > bv || (ov == bv && oi < bi)) { bv = ov; bi = oi; }
        }
        int wv = t >> 6;
        if ((t & 63) == 0) { rv[wv] = bv; ri[wv] = bi; }
        __syncthreads();
        if (t == 0) {
            for (int q = 1; q < 4; ++q) {
                float ov = rv[q]; int oi = ri[q];
                if (ov > bv || (ov == bv && oi < bi)) { bv = ov; bi = oi; }
            }
            ri[0] = bi;
            int outp = b * 7 + colbase + k;
            int gi   = goff + bi;
            out_idx_f[outp] = (float)gi;
            out_sc[outp]    = bv;
            ws_idx[outp]    = gi;
            soff[outp]      = coords[gi * 4 + 0] * 448 + coords[gi * 4 + 1];
        }
        __syncthreads();
        int sel = ri[0];
        int si = sel / side, sj = sel % side;
        float sx0 = si * 16.0f, sy0 = sj * 16.0f;
        float sx1 = sx0 + rs,   sy1 = sy0 + rs;
        for (int i = t; i < n; i += THREADS) {
            int ii = i / side, jj = i % side;
            float x0 = ii * 16.0f, y0 = jj * 16.0f;
            float x1 = x0 + rs,    y1 = y0 + rs;
            float xx0 = fmaxf(x0, sx0), yy0 = fmaxf(y0, sy0);
            float xx1 = fminf(x1, sx1), yy1 = fminf(y1, sy1);
            float w = xx1 - xx0 + 1.0f, h = yy1 - yy0 + 1.0f;
            float inter = (w < 0.0f || h < 0.0f) ? 0.0f : w * h;
            float iou = inter / (A + A - inter);
            if (iou > 0.25f) scl[i] = -INFINITY;
        }
        __syncthreads();
    }
}

// ---------------- Launch 3: persistent crop, T14 async-STAGE pipeline -----
// Task = (p, ch, 16-row stripe). Per iteration:
//   ds_write(regs of task i) -> lgkmcnt(0) -> raw s_barrier ->
//   issue task i+1 global loads -> compute task i (blend + 4 f32x4 stores).
// At the barrier there are NO outstanding vmem loads (prev loads consumed
// by ds_write) and the raw barrier skips the vmcnt(0) store drain; next
// loads land under the ~600-cycle compute phase.
__global__ __launch_bounds__(448) void crop_kernel(const float* __restrict__ x,
                                                   const int* __restrict__ soff,
                                                   float* __restrict__ out) {
    __shared__ float lds[2][924];
    int t = threadIdx.x;

    int rr0 = t / 132, xx0 = t - rr0 * 132;          // staged idx t
    int i1  = t + 448;
    int rr1 = i1 / 132, xx1 = i1 - rr1 * 132;        // staged idx t+448
    int xx2 = t + 104;                               // staged idx t+896 (rr=6, t<28)
    int row_sub = t / 56;                            // 0..7
    int seg     = t - row_sub * 56;                  // 0..55
    int ox0 = seg * 8;

    // ---- prologue: geometry + loads for task0 ----
    int task = blockIdx.x;
    int cw; float cscale, cwm1; int cS, crlo; float* coutb;
    float rA, rB, rC = 0.0f;
    {
        int p = task / 84, rem = task - p * 84;
        int ch = rem / 28, stripe = rem - ch * 28;
        int b = p / 7, col = p - b * 7;
        int g = (col < 2) ? 0 : ((col < 5) ? 1 : 2);
        cw = (g == 0) ? 64 : ((g == 1) ? 96 : 128);
        cscale = (float)cw * (1.0f / 448.0f);
        cwm1 = (float)(cw - 1);
        cS = stripe * 16;
        float syb = fminf(fmaxf(((float)cS + 0.5f) * cscale - 0.5f, 0.0f), cwm1);
        crlo = (int)syb;
        const float* cbase = x + ((size_t)(b * 3 + ch)) * 200704 + soff[p];
        coutb = out + ((size_t)(p * 3 + ch)) * 200704;
        rA = cbase[(size_t)min(crlo + rr0, cw - 1) * 448 + min(xx0, cw - 1)];
        rB = cbase[(size_t)min(crlo + rr1, cw - 1) * 448 + min(xx1, cw - 1)];
        if (t < 28)
            rC = cbase[(size_t)min(crlo + 6, cw - 1) * 448 + min(xx2, cw - 1)];
    }

    int buf = 0;
    while (true) {
        int nxt = task + CROP_GRID;
        bool has = nxt < NTASK;

        // next-task integer geometry + uniform soff load (s_load, issued early)
        int nw = 0, nrlo = 0, nS = 0, nso = 0, nb3 = 0, np3 = 0;
        float nscale = 0.0f, nwm1 = 0.0f;
        if (has) {
            int p = nxt / 84, rem = nxt - p * 84;
            int ch = rem / 28, stripe = rem - ch * 28;
            int b = p / 7, col = p - b * 7;
            int g = (col < 2) ? 0 : ((col < 5) ? 1 : 2);
            nw = (g == 0) ? 64 : ((g == 1) ? 96 : 128);
            nscale = (float)nw * (1.0f / 448.0f);
            nwm1 = (float)(nw - 1);
            nS = stripe * 16;
            float syb = fminf(fmaxf(((float)nS + 0.5f) * nscale - 0.5f, 0.0f), nwm1);
            nrlo = (int)syb;
            nso = soff[p];
            nb3 = b * 3 + ch;
            np3 = p * 3 + ch;
        }

        // stage current task (waits vmcnt on rA/rB/rC — covered by prev compute)
        lds[buf][t]       = rA;
        lds[buf][t + 448] = rB;
        if (t < 28) lds[buf][t + 896] = rC;
        asm volatile("s_waitcnt lgkmcnt(0)" ::: "memory");
        __builtin_amdgcn_s_barrier();

        // issue next-task loads (fly under compute below)
        float* noutb = nullptr;
        if (has) {
            const float* nbase = x + (size_t)nb3 * 200704 + nso;
            noutb = out + (size_t)np3 * 200704;
            rA = nbase[(size_t)min(nrlo + rr0, nw - 1) * 448 + min(xx0, nw - 1)];
            rB = nbase[(size_t)min(nrlo + rr1, nw - 1) * 448 + min(xx1, nw - 1)];
            if (t < 28)
                rC = nbase[(size_t)min(nrlo + 6, nw - 1) * 448 + min(xx2, nw - 1)];
        }

        // ---- compute current task from lds[buf] ----
        {
            float sxb = ((float)ox0 + 0.5f) * cscale - 0.5f;
            float sxc = fminf(fmaxf(sxb, 0.0f), cwm1);
            int   i0  = (int)sxc;
            float txk[8];
            bool  e1[8], e2[8];
            #pragma unroll
            for (int k = 0; k < 8; ++k) {
                float sx = fminf(fmaxf(sxb + (float)k * cscale, 0.0f), cwm1);
                int xi = (int)sx;
                txk[k] = sx - (float)xi;
                int d  = xi - i0;                  // 0, 1, or 2
                e1[k] = (d >= 1);
                e2[k] = (d >= 2);
            }
            const float* lbase = &lds[buf][0];
            #pragma unroll
            for (int half = 0; half < 2; ++half) {
                int oy = cS + half * 8 + row_sub;
                float sy = fminf(fmaxf(((float)oy + 0.5f) * cscale - 0.5f, 0.0f), cwm1);
                int   y0 = (int)sy;
                int   y1 = min(y0 + 1, cw - 1);
                float ty = sy - (float)y0;
                const float* l0 = lbase + (y0 - crlo) * 132 + i0;
                const float* l1 = lbase + (y1 - crlo) * 132 + i0;
                float a0 = l0[0], a1 = l0[1], a2 = l0[2], a3 = l0[3];
                float b0 = l1[0], b1 = l1[1], b2 = l1[2], b3 = l1[3];
                float da0 = a1 - a0, da1 = a2 - a1, da2 = a3 - a2;
                float db0 = b1 - b0, db1 = b2 - b1, db2 = b3 - b2;

                f32x4 res0, res1;
                #pragma unroll
                for (int k = 0; k < 8; ++k) {
                    float av  = e2[k] ? a2  : (e1[k] ? a1  : a0);
                    float dav = e2[k] ? da2 : (e1[k] ? da1 : da0);
                    float bv  = e2[k] ? b2  : (e1[k] ? b1  : b0);
                    float dbv = e2[k] ? db2 : (e1[k] ? db1 : db0);
                    float top = fmaf(txk[k], dav, av);
                    float bot = fmaf(txk[k], dbv, bv);
                    float rr  = top + ty * (bot - top);
                    if (k < 4) res0[k] = rr; else res1[k - 4] = rr;
                }
                float* orow = coutb + (size_t)oy * 448 + ox0;
                *(f32x4*)orow       = res0;
                *(f32x4*)(orow + 4) = res1;
            }
        }

        if (!has) break;
        cw = nw; cscale = nscale; cwm1 = nwm1; cS = nS; crlo = nrlo; coutb = noutb;
        task = nxt;
        buf ^= 1;
    }
}

extern "C" void kernel_launch(void* const* d_in, const int* in_sizes, int n_in,
                              void* d_out, int out_size, void* d_ws, size_t ws_size,
                              hipStream_t stream) {
    const float* x      = (const float*)d_in[0];   // (8,3,448,448)
    const float* fm     = (const float*)d_in[1];   // (8,384,28,28)
    const float* emb    = (const float*)d_in[2];   // (8,2048)
    const float* Wc     = (const float*)d_in[3];   // (2048,200)
    const float* bc     = (const float*)d_in[4];   // (200,)
    const int*   coords = (const int*)d_in[5];     // (1595,4)

    float* out        = (float*)d_out;
    float* out_idx    = out;                  // 56  (indices, stored as float)
    float* out_sc     = out + 56;             // 56
    float* all_scores = out + 112;            // 12760
    float* imgs       = out + 12872;          // 33718272
    float* logits     = out + 33731144;       // 1600

    int K = 32;
    while (K > 1 && ws_size < 1024 + (size_t)8 * K * 784 * 4 + 25600 * 4) K >>= 1;
    int cpc = 384 / K;

    int*    ws_idx = (int*)d_ws;                                   // 56 ints @ 0
    int*    soff   = (int*)((char*)d_ws + 256);                    // 56 ints @ 256
    float4* part   = (float4*)((char*)d_ws + 1024);                // 8*K*196 float4
    float*  lpart  = (float*)((char*)d_ws + 1024 + (size_t)8 * K * 784 * 4);

    fused1_kernel<<<8 * K + 128, THREADS, 0, stream>>>(fm, part, cpc, K, emb, Wc, lpart);
    fused2_kernel<<<32, THREADS, 0, stream>>>(part, K, all_scores, out_idx, out_sc, ws_idx,
                                              soff, coords, lpart, bc, logits);
    crop_kernel<<<CROP_GRID, 448, 0, stream>>>(x, soff, imgs);
}